// Round 10
// baseline (2163.874 us; speedup 1.0000x reference)
//
#include <hip/hip_runtime.h>

#define B_ 64
#define T_ 512
#define I_ 256
#define H_ 1024
#define O_ 256

#define NCLUST 4
#define WPC 64        // workgroups per cluster (r6 geometry: the validated optimum)
#define MB 16         // batches per cluster
#define ROWS 16       // h-rows per WG
#define SENT 0x7FFF7FFFu   // f16 NaN pair: tanh output can never equal this

typedef _Float16 f16;
typedef _Float16 f16x2 __attribute__((ext_vector_type(2)));
typedef _Float16 f16x4 __attribute__((ext_vector_type(4)));
typedef _Float16 half8 __attribute__((ext_vector_type(8)));
typedef float floatx4 __attribute__((ext_vector_type(4)));
typedef unsigned int uint4v __attribute__((ext_vector_type(4)));

// ---------- memory helpers ----------
// sc0 sc1: bypass L1+L2, access MALL (device coherence point) — the only sound
// path for sentinel-polled data (r8 lesson: cached reads install stale lines).
__device__ __forceinline__ uint4v load_uc16(const void* p) {
  uint4v r;
  asm volatile("global_load_dwordx4 %0, %1, off sc0 sc1" : "=v"(r) : "v"(p));
  return r;
}
__device__ __forceinline__ void store_uc4(void* p, unsigned v) {
  asm volatile("global_store_dword %0, %1, off sc0 sc1" :: "v"(p), "v"(v) : "memory");
}
__device__ __forceinline__ void store_uc16(void* p, uint4v v) {
  asm volatile("global_store_dwordx4 %0, %1, off sc0 sc1" :: "v"(p), "v"(v) : "memory");
}
__device__ __forceinline__ unsigned pack_f16x2(float a, float b) {
  f16x2 t; t[0] = (f16)a; t[1] = (f16)b;
  return __builtin_bit_cast(unsigned, t);
}

// fast tanh: 1 - 2/(e^(2x)+1) via v_exp_f32 + v_rcp_f32 (err ~1e-7, f16 target 5e-4)
__device__ __forceinline__ float fast_tanh(float x) {
#if __has_builtin(__builtin_amdgcn_exp2f) && __has_builtin(__builtin_amdgcn_rcpf)
  float e = __builtin_amdgcn_exp2f(x * 2.8853900817779268f);  // 2*log2(e)
  return 1.0f - 2.0f * __builtin_amdgcn_rcpf(e + 1.0f);
#else
  return tanhf(x);
#endif
}

#if __has_builtin(__builtin_amdgcn_fdot2)
__device__ __forceinline__ float dot2f(f16x2 a, f16x2 b, float c) {
  return __builtin_amdgcn_fdot2(a, b, c, false);
}
#else
__device__ __forceinline__ float dot2f(f16x2 a, f16x2 b, float c) {
  return fmaf((float)a[0], (float)b[0], fmaf((float)a[1], (float)b[1], c));
}
#endif

__device__ __forceinline__ float dot8f(half8 w, half8 v, float acc) {
  acc = dot2f(__builtin_shufflevector(w, w, 0, 1), __builtin_shufflevector(v, v, 0, 1), acc);
  acc = dot2f(__builtin_shufflevector(w, w, 2, 3), __builtin_shufflevector(v, v, 2, 3), acc);
  acc = dot2f(__builtin_shufflevector(w, w, 4, 5), __builtin_shufflevector(v, v, 4, 5), acc);
  acc = dot2f(__builtin_shufflevector(w, w, 6, 7), __builtin_shufflevector(v, v, 6, 7), acc);
  return acc;
}

// ---------- converters / init ----------
__global__ void cast_f16(const float* __restrict__ src, f16* __restrict__ dst, int n4) {
  int i = blockIdx.x * blockDim.x + threadIdx.x;
  if (i >= n4) return;
  float4 a = reinterpret_cast<const float4*>(src)[i];
  f16x4 v;
  v[0] = (f16)a.x; v[1] = (f16)a.y; v[2] = (f16)a.z; v[3] = (f16)a.w;
  reinterpret_cast<f16x4*>(dst)[i] = v;
}

__global__ void convert_T8(const float* __restrict__ src, f16* __restrict__ dst,
                           int R, int K) {
  int K8 = K >> 3;
  int total = R * K8;
  int idx = blockIdx.x * blockDim.x + threadIdx.x;
  if (idx >= total) return;
  int r = idx / K8;
  int k8 = idx - r * K8;
  const float4* s = reinterpret_cast<const float4*>(src + (size_t)r * K + (size_t)k8 * 8);
  float4 a = s[0], b = s[1];
  half8 v;
  v[0] = (f16)a.x; v[1] = (f16)a.y; v[2] = (f16)a.z; v[3] = (f16)a.w;
  v[4] = (f16)b.x; v[5] = (f16)b.y; v[6] = (f16)b.z; v[7] = (f16)b.w;
  reinterpret_cast<half8*>(dst)[(size_t)k8 * R + r] = v;
}

// sentinel-fill hseq via MALL bypass stores; re-run every launch (replay-safe)
__global__ void init_hseq(unsigned* __restrict__ p, long n16) {
  uint4v sv; sv[0] = SENT; sv[1] = SENT; sv[2] = SENT; sv[3] = SENT;
  long i = (long)blockIdx.x * blockDim.x + threadIdx.x;
  const long stride = (long)gridDim.x * blockDim.x;
  for (; i < n16; i += stride) store_uc16(p + 4 * i, sv);
}

// ---------- tier-1 recurrent kernel: r6 protocol + overlapped poll/MFMA + fast tanh ----------
// grid 256 x 256 thr. Cluster c = wg&3 owns batches [c*16,+16); worker w = wg>>2
// owns h rows [w*16,+16). W_hh/W_ih slices stationary in VGPRs; h[s] in hseq[s-1]
// (unique per step, sentinel-filled). Producer: bypass-store h, fire-and-forget.
// Consumer: selective per-packet reload; a packet that goes wave-valid is MFMA'd
// IMMEDIATELY (overlapping retry RTT). Determinism: per-packet accumulator pk[i]
// (order of MFMA execution varies; each packet hits its fixed slot once; final
// sum is a fixed-order tree).
__global__ __launch_bounds__(256) void rnn10(
    const f16* __restrict__ whh,   // [H][H] f16
    const f16* __restrict__ wih,   // [H][I] f16
    const f16* __restrict__ xbf,   // [B][T][I] f16
    const float* __restrict__ bih,
    const float* __restrict__ bhh,
    f16* __restrict__ hseq) {      // [T][NCLUST][MB][H] f16 (sentinel-filled)
  const int wg = blockIdx.x;
  const int c = wg & 3;
  const int w = wg >> 2;
  const int tid = threadIdx.x;
  const int wv = tid >> 6;
  const int lane = tid & 63;
  const int lr = lane & 15;
  const int kb = lane >> 4;
  const int n0 = w * ROWS;
  const int b0 = c * MB;

  // stationary B-fragments
  half8 bfh[8];
#pragma unroll
  for (int i = 0; i < 8; ++i) {
    const int k = wv * 256 + i * 32 + kb * 8;
    bfh[i] = *reinterpret_cast<const half8*>(&whh[(size_t)(n0 + lr) * H_ + k]);
  }
  half8 bfx[2];
#pragma unroll
  for (int j = 0; j < 2; ++j) {
    const int k = wv * 64 + j * 32 + kb * 8;
    bfx[j] = *reinterpret_cast<const half8*>(&wih[(size_t)(n0 + lr) * I_ + k]);
  }

  // output ownership after K-split reduce (validated mapping)
  const int m = ((lane >> 4) << 2) | wv;
  const int nl = lane & 15;
  const float bias = bih[n0 + nl] + bhh[n0 + nl];

  const f16* xrow = xbf + (size_t)(b0 + lr) * T_ * I_ + wv * 64 + kb * 8;

  __shared__ floatx4 red[2][4][64];   // parity double-buffer: 1 barrier/step
  const size_t CST = (size_t)NCLUST * MB * H_;
  const size_t coff = (size_t)c * MB * H_;

  for (int s = 1; s <= T_; ++s) {
    // x part (cached loads; LLC-resident), folded into pk[0]/pk[1]
    const f16* xs = xrow + (size_t)(s - 1) * I_;
    half8 ax0 = *reinterpret_cast<const half8*>(xs);
    half8 ax1 = *reinterpret_cast<const half8*>(xs + 32);

    floatx4 pk[8];
#pragma unroll
    for (int i = 0; i < 8; ++i) pk[i] = floatx4{0.f, 0.f, 0.f, 0.f};
    pk[0] = __builtin_amdgcn_mfma_f32_16x16x32_f16(ax0, bfx[0], pk[0], 0, 0, 0);
    pk[1] = __builtin_amdgcn_mfma_f32_16x16x32_f16(ax1, bfx[1], pk[1], 0, 0, 0);

    if (s > 1) {
      const f16* hr = hseq + (size_t)(s - 2) * CST + coff;  // h[s-1]
      uint4v af[8];
      unsigned need = 0xFFu;   // per-lane: my 16B of packet i still sentinel
      unsigned done = 0u;      // wave-uniform: packet i already MFMA'd
      int g = 0;
      for (;;) {
        // 1) issue (re)loads for per-lane-needed packets (exec-masked)
#pragma unroll
        for (int i = 0; i < 8; ++i) {
          if (need & (1u << i)) {
            af[i] = load_uc16(&hr[(size_t)lr * H_ + wv * 256 + i * 32 + kb * 8]);
          }
        }
        // 2) MFMA packets that were already wave-valid (overlaps reload RTT)
#pragma unroll
        for (int i = 0; i < 8; ++i) {
          if (!(done & (1u << i))) {
            if (__ballot((need & (1u << i)) == 0u) == ~0ull) {
              pk[i] = __builtin_amdgcn_mfma_f32_16x16x32_f16(
                  __builtin_bit_cast(half8, af[i]), bfh[i], pk[i], 0, 0, 0);
              done |= (1u << i);
            }
          }
        }
        if (done == 0xFFu) break;
        // 3) wait for this round's loads, validate
        asm volatile("s_waitcnt vmcnt(0)" ::: "memory");
#pragma unroll
        for (int i = 0; i < 8; ++i) {
          if (need & (1u << i)) {
            unsigned bad = (unsigned)(af[i][0] == SENT) | (unsigned)(af[i][1] == SENT) |
                           (unsigned)(af[i][2] == SENT) | (unsigned)(af[i][3] == SENT);
            if (!bad) need &= ~(1u << i);
          }
        }
        // 4) MFMA freshly wave-valid packets (fast path: all done in round 1)
#pragma unroll
        for (int i = 0; i < 8; ++i) {
          if (!(done & (1u << i))) {
            if (__ballot((need & (1u << i)) == 0u) == ~0ull) {
              pk[i] = __builtin_amdgcn_mfma_f32_16x16x32_f16(
                  __builtin_bit_cast(half8, af[i]), bfh[i], pk[i], 0, 0, 0);
              done |= (1u << i);
            }
          }
        }
        if (done == 0xFFu) break;
        if (++g > (1 << 13)) break;   // fail-fast valve (validation catches)
        __builtin_amdgcn_s_sleep(1);
      }
      __builtin_amdgcn_sched_barrier(0);
    }

    // K-split reduce (fixed-order sum tree -> deterministic)
    const int pr = s & 1;
    red[pr][wv][lane] =
        ((pk[0] + pk[1]) + (pk[2] + pk[3])) + ((pk[4] + pk[5]) + (pk[6] + pk[7]));
    __syncthreads();

    float v = red[pr][0][lane][wv] + red[pr][1][lane][wv] +
              red[pr][2][lane][wv] + red[pr][3][lane][wv] + bias;
    float hn = fast_tanh(v);
    float po = __shfl_xor(hn, 1);
    f16* hw = hseq + (size_t)(s - 1) * CST + coff;
    if (!(lane & 1)) {
      store_uc4(&hw[(size_t)m * H_ + n0 + nl], pack_f16x2(hn, po));
    }
    // fire-and-forget: data IS the flag.
  }
}

// FC head over flat h_last rows: row b at hlast + b*H_
__global__ __launch_bounds__(256) void fc_head_flat(
    const f16* __restrict__ hlast, const f16* __restrict__ wfcT,
    const float* __restrict__ bfc, float* __restrict__ out) {
  __shared__ f16 hs[H_];
  const int b = blockIdx.x;
  const int o = threadIdx.x;
  reinterpret_cast<f16x4*>(hs)[o] =
      reinterpret_cast<const f16x4*>(hlast + (size_t)b * H_)[o];
  __syncthreads();
  float acc = bfc[o];
  const half8* wp = reinterpret_cast<const half8*>(wfcT) + o;
  const half8* hv = reinterpret_cast<const half8*>(hs);
#pragma unroll 8
  for (int c8 = 0; c8 < H_ / 8; ++c8) acc = dot8f(wp[(size_t)c8 * O_], hv[c8], acc);
  out[(size_t)b * O_ + o] = acc;
}

// ---------- tier-3: round-1 weight-streaming (3 MB ws) ----------
__global__ __launch_bounds__(1024) void rnn_f16(
    const float* __restrict__ x, const f16* __restrict__ wihT,
    const f16* __restrict__ whhT, const float* __restrict__ bih,
    const float* __restrict__ bhh, const f16* __restrict__ wfcT,
    const float* __restrict__ bfc, float* __restrict__ out) {
  __shared__ f16 hs[H_];
  __shared__ f16 xs[I_];
  const int b = blockIdx.x;
  const int j = threadIdx.x;
  const float bias = bih[j] + bhh[j];
  hs[j] = (f16)0.f;
  const half8* wih_p = reinterpret_cast<const half8*>(wihT) + j;
  const half8* whh_p = reinterpret_cast<const half8*>(whhT) + j;
  const half8* xv = reinterpret_cast<const half8*>(xs);
  const half8* hv = reinterpret_cast<const half8*>(hs);
  const float* xrow = x + (size_t)b * T_ * I_;
  for (int t = 0; t < T_; ++t) {
    if (j < I_) xs[j] = (f16)xrow[t * I_ + j];
    __syncthreads();
    float acc = bias;
#pragma unroll 8
    for (int c = 0; c < I_ / 8; ++c) acc = dot8f(wih_p[c * H_], xv[c], acc);
#pragma unroll 8
    for (int c = 0; c < H_ / 8; ++c) acc = dot8f(whh_p[c * H_], hv[c], acc);
    float hn = tanhf(acc);
    __syncthreads();
    hs[j] = (f16)hn;
  }
  __syncthreads();
  if (j < O_) {
    const half8* wfc_p = reinterpret_cast<const half8*>(wfcT) + j;
    float acc = bfc[j];
#pragma unroll 8
    for (int c = 0; c < H_ / 8; ++c) acc = dot8f(wfc_p[c * O_], hv[c], acc);
    out[(size_t)b * O_ + j] = acc;
  }
}

// ---------- tier-4: fp32, zero ws ----------
__global__ __launch_bounds__(1024) void rnn_fp32(
    const float* __restrict__ x,
    const float* __restrict__ Wih, const float* __restrict__ Whh,
    const float* __restrict__ bih, const float* __restrict__ bhh,
    const float* __restrict__ Wfc, const float* __restrict__ bfc,
    float* __restrict__ out) {
  __shared__ float hs[H_];
  __shared__ float xs[I_];
  const int b = blockIdx.x;
  const int j = threadIdx.x;
  const float bias = bih[j] + bhh[j];
  hs[j] = 0.f;
  const float4* wih_r = reinterpret_cast<const float4*>(Wih + (size_t)j * I_);
  const float4* whh_r = reinterpret_cast<const float4*>(Whh + (size_t)j * H_);
  const float4* xv = reinterpret_cast<const float4*>(xs);
  const float4* hv = reinterpret_cast<const float4*>(hs);
  const float* xrow = x + (size_t)b * T_ * I_;
  for (int t = 0; t < T_; ++t) {
    if (j < I_) xs[j] = xrow[t * I_ + j];
    __syncthreads();
    float acc = bias;
#pragma unroll 4
    for (int c = 0; c < I_ / 4; ++c) {
      float4 w = wih_r[c], v = xv[c];
      acc = fmaf(w.x, v.x, acc); acc = fmaf(w.y, v.y, acc);
      acc = fmaf(w.z, v.z, acc); acc = fmaf(w.w, v.w, acc);
    }
#pragma unroll 4
    for (int c = 0; c < H_ / 4; ++c) {
      float4 w = whh_r[c], v = hv[c];
      acc = fmaf(w.x, v.x, acc); acc = fmaf(w.y, v.y, acc);
      acc = fmaf(w.z, v.z, acc); acc = fmaf(w.w, v.w, acc);
    }
    float hn = tanhf(acc);
    __syncthreads();
    hs[j] = hn;
  }
  __syncthreads();
  if (j < O_) {
    float acc = bfc[j];
    const float4* wfc_r = reinterpret_cast<const float4*>(Wfc + (size_t)j * H_);
    for (int c = 0; c < H_ / 4; ++c) {
      float4 w = wfc_r[c], v = hv[c];
      acc = fmaf(w.x, v.x, acc); acc = fmaf(w.y, v.y, acc);
      acc = fmaf(w.z, v.z, acc); acc = fmaf(w.w, v.w, acc);
    }
    out[(size_t)b * O_ + j] = acc;
  }
}

extern "C" void kernel_launch(void* const* d_in, const int* in_sizes, int n_in,
                              void* d_out, int out_size, void* d_ws, size_t ws_size,
                              hipStream_t stream) {
  const float* x   = (const float*)d_in[0];
  const float* Wih = (const float*)d_in[1];
  const float* Whh = (const float*)d_in[2];
  const float* bih = (const float*)d_in[3];
  const float* bhh = (const float*)d_in[4];
  const float* Wfc = (const float*)d_in[5];
  const float* bfc = (const float*)d_in[6];
  float* out = (float*)d_out;

  const size_t n_whh = (size_t)H_ * H_;
  const size_t n_wih = (size_t)H_ * I_;
  const size_t n_wfc = (size_t)O_ * H_;
  const size_t n_x   = (size_t)B_ * T_ * I_;
  const size_t n_hseq = (size_t)T_ * NCLUST * MB * H_;
  const int thr = 256;

  // ---- tier 1 layout: whh | wih | wfcT | xbf | hseq  (~83 MB)
  {
    size_t off = 0;
    const size_t o_whh = off; off += n_whh;
    const size_t o_wih = off; off += n_wih;
    const size_t o_wfc = off; off += n_wfc;
    const size_t o_x   = off; off += n_x;
    const size_t o_hs  = off; off += n_hseq;
    const size_t need1 = off * sizeof(f16);

    if (ws_size >= need1) {
      f16* wsf   = (f16*)d_ws;
      f16* whh_h = wsf + o_whh;
      f16* wih_h = wsf + o_wih;
      f16* wfcT  = wsf + o_wfc;
      f16* xbf   = wsf + o_x;
      f16* hseq  = wsf + o_hs;

      const long n16 = (long)(n_hseq * sizeof(f16) / 16);
      init_hseq<<<4096, thr, 0, stream>>>((unsigned*)hseq, n16);
      cast_f16<<<(int)(n_whh / 4 / thr), thr, 0, stream>>>(Whh, whh_h, (int)(n_whh / 4));
      cast_f16<<<(int)(n_wih / 4 / thr), thr, 0, stream>>>(Wih, wih_h, (int)(n_wih / 4));
      cast_f16<<<(int)(n_x / 4 / thr), thr, 0, stream>>>(x, xbf, (int)(n_x / 4));
      convert_T8<<<(int)(n_wfc / 8 / thr), thr, 0, stream>>>(Wfc, wfcT, O_, H_);

      rnn10<<<NCLUST * WPC, thr, 0, stream>>>(whh_h, wih_h, xbf, bih, bhh, hseq);
      const f16* hlast = hseq + (size_t)(T_ - 1) * NCLUST * MB * H_;
      fc_head_flat<<<B_, O_, 0, stream>>>(hlast, wfcT, bfc, out);
      return;
    }
  }

  // ---- tier 3 (3 MB) / tier 4 (0)
  if (ws_size >= (n_wih + n_whh + n_wfc) * sizeof(f16)) {
    f16* wihT = (f16*)d_ws;
    f16* whhT = wihT + n_wih;
    f16* wfcT = whhT + n_whh;
    convert_T8<<<(int)((n_wih / 8 + thr - 1) / thr), thr, 0, stream>>>(Wih, wihT, H_, I_);
    convert_T8<<<(int)((n_whh / 8 + thr - 1) / thr), thr, 0, stream>>>(Whh, whhT, H_, H_);
    convert_T8<<<(int)((n_wfc / 8 + thr - 1) / thr), thr, 0, stream>>>(Wfc, wfcT, O_, H_);
    rnn_f16<<<B_, 1024, 0, stream>>>(x, wihT, whhT, bih, bhh, wfcT, bfc, out);
  } else {
    rnn_fp32<<<B_, 1024, 0, stream>>>(x, Wih, Whh, bih, bhh, Wfc, bfc, out);
  }
}

// Round 11
// 1564.734 us; speedup vs baseline: 1.3829x; 1.3829x over previous
//
#include <hip/hip_runtime.h>

#define B_ 64
#define T_ 512
#define I_ 256
#define H_ 1024
#define O_ 256

#define NCLUST 4
#define WPC 64        // workgroups per cluster (validated optimum: r6 vs r8/r9)
#define MB 16         // batches per cluster
#define ROWS 16       // h-rows per WG
#define NMF_H 8       // h-part MFMAs per wave (K=256)
#define NMF_X 2       // x-part MFMAs per wave (K=64)
#define KPW_H 256
#define KPW_X 64
#define SENT 0x7FFF7FFFu   // f16 NaN pair: tanh output can never equal this

typedef _Float16 f16;
typedef _Float16 f16x2 __attribute__((ext_vector_type(2)));
typedef _Float16 f16x4 __attribute__((ext_vector_type(4)));
typedef _Float16 half8 __attribute__((ext_vector_type(8)));
typedef float floatx4 __attribute__((ext_vector_type(4)));
typedef unsigned int uint4v __attribute__((ext_vector_type(4)));

// ---------- memory helpers ----------
// sc0 sc1: bypass L1+L2, access MALL (device coherence point) — the only sound
// path for sentinel-polled data (r8 lesson: cached reads install stale lines).
__device__ __forceinline__ uint4v load_uc16(const void* p) {
  uint4v r;
  asm volatile("global_load_dwordx4 %0, %1, off sc0 sc1" : "=v"(r) : "v"(p));
  return r;
}
__device__ __forceinline__ void store_uc4(void* p, unsigned v) {
  asm volatile("global_store_dword %0, %1, off sc0 sc1" :: "v"(p), "v"(v) : "memory");
}
__device__ __forceinline__ void store_uc16(void* p, uint4v v) {
  asm volatile("global_store_dwordx4 %0, %1, off sc0 sc1" :: "v"(p), "v"(v) : "memory");
}
__device__ __forceinline__ unsigned pack_f16x2(float a, float b) {
  f16x2 t; t[0] = (f16)a; t[1] = (f16)b;
  return __builtin_bit_cast(unsigned, t);
}

// fast tanh: 1 - 2/(e^(2x)+1) via v_exp_f32 + v_rcp_f32 (validated r10: absmax 0.00195)
__device__ __forceinline__ float fast_tanh(float x) {
#if __has_builtin(__builtin_amdgcn_exp2f) && __has_builtin(__builtin_amdgcn_rcpf)
  float e = __builtin_amdgcn_exp2f(x * 2.8853900817779268f);  // 2*log2(e)
  return 1.0f - 2.0f * __builtin_amdgcn_rcpf(e + 1.0f);
#else
  return tanhf(x);
#endif
}

#if __has_builtin(__builtin_amdgcn_fdot2)
__device__ __forceinline__ float dot2f(f16x2 a, f16x2 b, float c) {
  return __builtin_amdgcn_fdot2(a, b, c, false);
}
#else
__device__ __forceinline__ float dot2f(f16x2 a, f16x2 b, float c) {
  return fmaf((float)a[0], (float)b[0], fmaf((float)a[1], (float)b[1], c));
}
#endif

__device__ __forceinline__ float dot8f(half8 w, half8 v, float acc) {
  acc = dot2f(__builtin_shufflevector(w, w, 0, 1), __builtin_shufflevector(v, v, 0, 1), acc);
  acc = dot2f(__builtin_shufflevector(w, w, 2, 3), __builtin_shufflevector(v, v, 2, 3), acc);
  acc = dot2f(__builtin_shufflevector(w, w, 4, 5), __builtin_shufflevector(v, v, 4, 5), acc);
  acc = dot2f(__builtin_shufflevector(w, w, 6, 7), __builtin_shufflevector(v, v, 6, 7), acc);
  return acc;
}

// ---------- converters / init ----------
__global__ void cast_f16(const float* __restrict__ src, f16* __restrict__ dst, int n4) {
  int i = blockIdx.x * blockDim.x + threadIdx.x;
  if (i >= n4) return;
  float4 a = reinterpret_cast<const float4*>(src)[i];
  f16x4 v;
  v[0] = (f16)a.x; v[1] = (f16)a.y; v[2] = (f16)a.z; v[3] = (f16)a.w;
  reinterpret_cast<f16x4*>(dst)[i] = v;
}

__global__ void convert_T8(const float* __restrict__ src, f16* __restrict__ dst,
                           int R, int K) {
  int K8 = K >> 3;
  int total = R * K8;
  int idx = blockIdx.x * blockDim.x + threadIdx.x;
  if (idx >= total) return;
  int r = idx / K8;
  int k8 = idx - r * K8;
  const float4* s = reinterpret_cast<const float4*>(src + (size_t)r * K + (size_t)k8 * 8);
  float4 a = s[0], b = s[1];
  half8 v;
  v[0] = (f16)a.x; v[1] = (f16)a.y; v[2] = (f16)a.z; v[3] = (f16)a.w;
  v[4] = (f16)b.x; v[5] = (f16)b.y; v[6] = (f16)b.z; v[7] = (f16)b.w;
  reinterpret_cast<half8*>(dst)[(size_t)k8 * R + r] = v;
}

// sentinel-fill hseq via MALL bypass stores; re-run every launch (replay-safe)
__global__ void init_hseq(unsigned* __restrict__ p, long n16) {
  uint4v sv; sv[0] = SENT; sv[1] = SENT; sv[2] = SENT; sv[3] = SENT;
  long i = (long)blockIdx.x * blockDim.x + threadIdx.x;
  const long stride = (long)gridDim.x * blockDim.x;
  for (; i < n16; i += stride) store_uc16(p + 4 * i, sv);
}

// ---------- tier-1 recurrent kernel: r6 sentinel dataflow + line prefetch + fast tanh ----------
// grid 256 x 256 thr. Cluster c = wg&3 owns batches [c*16,+16); worker w = wg>>2
// owns h rows [w*16,+16). W_hh/W_ih slices stationary in VGPRs; h[s] in hseq[s-1]
// (unique per step, sentinel-filled). Producer: bypass-store h, fire-and-forget
// (data IS the flag). Consumer: merged poll+load from MALL, retry until no
// sentinel dword. NEW: at step s each wave issues 8 DISCARDED bypass loads of
// its step-(s+1) read-set (hseq[s-1]) — installs those lines in MALL ~2 us
// before they're polled, so the next step's first poll round is a MALL hit
// instead of an HBM miss (r6 FETCH evidence: 64 MB = whole hseq fetched once).
// Safe: producers' dword stores update MALL-resident lines (proven by r6
// passing while consumers race-install lines); poll still validates all dwords.
__global__ __launch_bounds__(256) void rnn11(
    const f16* __restrict__ whh,   // [H][H] f16
    const f16* __restrict__ wih,   // [H][I] f16
    const f16* __restrict__ xbf,   // [B][T][I] f16
    const float* __restrict__ bih,
    const float* __restrict__ bhh,
    f16* __restrict__ hseq) {      // [T][NCLUST][MB][H] f16 (sentinel-filled)
  const int wg = blockIdx.x;
  const int c = wg & 3;
  const int w = wg >> 2;
  const int tid = threadIdx.x;
  const int wv = tid >> 6;
  const int lane = tid & 63;
  const int lr = lane & 15;
  const int kb = lane >> 4;
  const int n0 = w * ROWS;
  const int b0 = c * MB;

  // stationary B-fragments
  half8 bfh[NMF_H];
#pragma unroll
  for (int i = 0; i < NMF_H; ++i) {
    const int k = wv * KPW_H + i * 32 + kb * 8;
    bfh[i] = *reinterpret_cast<const half8*>(&whh[(size_t)(n0 + lr) * H_ + k]);
  }
  half8 bfx[NMF_X];
#pragma unroll
  for (int i = 0; i < NMF_X; ++i) {
    const int k = wv * KPW_X + i * 32 + kb * 8;
    bfx[i] = *reinterpret_cast<const half8*>(&wih[(size_t)(n0 + lr) * I_ + k]);
  }

  // output ownership after the K-split reduce (validated mapping)
  const int m = ((lane >> 4) << 2) | wv;
  const int nl = lane & 15;
  const float bias = bih[n0 + nl] + bhh[n0 + nl];

  const f16* xrow = xbf + (size_t)(b0 + lr) * T_ * I_ + wv * KPW_X + kb * 8;

  __shared__ floatx4 red[2][4][64];   // parity double-buffer: 1 barrier/step
  const size_t CST = (size_t)NCLUST * MB * H_;
  const size_t coff = (size_t)c * MB * H_;

  for (int s = 1; s <= T_; ++s) {
    // x loads (cached) issued first: latency hides under the poll
    const f16* xs = xrow + (size_t)(s - 1) * I_;
    half8 ax0 = *reinterpret_cast<const half8*>(xs);
    half8 ax1 = *reinterpret_cast<const half8*>(xs + 32);

    // sentinel-line PREFETCH: install next step's read-set (hseq[s-1]) in MALL.
    // Results discarded; the poll below revalidates everything.
    if (s < T_) {
      const f16* pn = hseq + (size_t)(s - 1) * CST + coff;
#pragma unroll
      for (int i = 0; i < NMF_H; ++i) {
        uint4v dummy;
        asm volatile("global_load_dwordx4 %0, %1, off sc0 sc1"
                     : "=v"(dummy)
                     : "v"(&pn[(size_t)lr * H_ + wv * KPW_H + i * 32 + kb * 8]));
        (void)dummy;
      }
    }

    floatx4 acc0 = {0.f, 0.f, 0.f, 0.f}, acc1 = {0.f, 0.f, 0.f, 0.f};
    acc0 = __builtin_amdgcn_mfma_f32_16x16x32_f16(ax0, bfx[0], acc0, 0, 0, 0);
    acc1 = __builtin_amdgcn_mfma_f32_16x16x32_f16(ax1, bfx[1], acc1, 0, 0, 0);

    if (s > 1) {
      const f16* hr = hseq + (size_t)(s - 2) * CST + coff;  // h[s-1]
      uint4v af[NMF_H];
      int g = 0;
      for (;;) {
        // merged poll+load: fetch all 8 packets from MALL
#pragma unroll
        for (int i = 0; i < NMF_H; ++i) {
          const int k = wv * KPW_H + i * 32 + kb * 8;
          af[i] = load_uc16(&hr[(size_t)lr * H_ + k]);
        }
        asm volatile("s_waitcnt vmcnt(0)" ::: "memory");
        unsigned bad = 0u;
#pragma unroll
        for (int i = 0; i < NMF_H; ++i) {
          bad |= (unsigned)(af[i][0] == SENT);
          bad |= (unsigned)(af[i][1] == SENT);
          bad |= (unsigned)(af[i][2] == SENT);
          bad |= (unsigned)(af[i][3] == SENT);
        }
        if (__all(bad == 0u)) break;            // all dwords written -> data valid
        if (++g > (1 << 14)) break;             // fail-fast valve (no hang)
        __builtin_amdgcn_s_sleep(1);
      }
      __builtin_amdgcn_sched_barrier(0);
#pragma unroll
      for (int i = 0; i < NMF_H; ++i) {
        half8 a = __builtin_bit_cast(half8, af[i]);
        if (i & 1) acc1 = __builtin_amdgcn_mfma_f32_16x16x32_f16(a, bfh[i], acc1, 0, 0, 0);
        else       acc0 = __builtin_amdgcn_mfma_f32_16x16x32_f16(a, bfh[i], acc0, 0, 0, 0);
      }
    }

    // K-split reduce (parity-buffered: single barrier per step)
    const int pr = s & 1;
    red[pr][wv][lane] = acc0 + acc1;
    __syncthreads();

    float v = red[pr][0][lane][wv] + red[pr][1][lane][wv] +
              red[pr][2][lane][wv] + red[pr][3][lane][wv] + bias;
    float hn = fast_tanh(v);
    float po = __shfl_xor(hn, 1);
    f16* hw = hseq + (size_t)(s - 1) * CST + coff;
    if (!(lane & 1)) {
      store_uc4(&hw[(size_t)m * H_ + n0 + nl], pack_f16x2(hn, po));
    }
    // fire-and-forget: no ack, no flag, no trailing barrier.
  }
}

// FC head over flat h_last rows: row b at hlast + b*H_
__global__ __launch_bounds__(256) void fc_head_flat(
    const f16* __restrict__ hlast, const f16* __restrict__ wfcT,
    const float* __restrict__ bfc, float* __restrict__ out) {
  __shared__ f16 hs[H_];
  const int b = blockIdx.x;
  const int o = threadIdx.x;
  reinterpret_cast<f16x4*>(hs)[o] =
      reinterpret_cast<const f16x4*>(hlast + (size_t)b * H_)[o];
  __syncthreads();
  float acc = bfc[o];
  const half8* wp = reinterpret_cast<const half8*>(wfcT) + o;
  const half8* hv = reinterpret_cast<const half8*>(hs);
#pragma unroll 8
  for (int c8 = 0; c8 < H_ / 8; ++c8) acc = dot8f(wp[(size_t)c8 * O_], hv[c8], acc);
  out[(size_t)b * O_ + o] = acc;
}

// ---------- tier-3: round-1 weight-streaming (3 MB ws) ----------
__global__ __launch_bounds__(1024) void rnn_f16(
    const float* __restrict__ x, const f16* __restrict__ wihT,
    const f16* __restrict__ whhT, const float* __restrict__ bih,
    const float* __restrict__ bhh, const f16* __restrict__ wfcT,
    const float* __restrict__ bfc, float* __restrict__ out) {
  __shared__ f16 hs[H_];
  __shared__ f16 xs[I_];
  const int b = blockIdx.x;
  const int j = threadIdx.x;
  const float bias = bih[j] + bhh[j];
  hs[j] = (f16)0.f;
  const half8* wih_p = reinterpret_cast<const half8*>(wihT) + j;
  const half8* whh_p = reinterpret_cast<const half8*>(whhT) + j;
  const half8* xv = reinterpret_cast<const half8*>(xs);
  const half8* hv = reinterpret_cast<const half8*>(hs);
  const float* xrow = x + (size_t)b * T_ * I_;
  for (int t = 0; t < T_; ++t) {
    if (j < I_) xs[j] = (f16)xrow[t * I_ + j];
    __syncthreads();
    float acc = bias;
#pragma unroll 8
    for (int c = 0; c < I_ / 8; ++c) acc = dot8f(wih_p[c * H_], xv[c], acc);
#pragma unroll 8
    for (int c = 0; c < H_ / 8; ++c) acc = dot8f(whh_p[c * H_], hv[c], acc);
    float hn = tanhf(acc);
    __syncthreads();
    hs[j] = (f16)hn;
  }
  __syncthreads();
  if (j < O_) {
    const half8* wfc_p = reinterpret_cast<const half8*>(wfcT) + j;
    float acc = bfc[j];
#pragma unroll 8
    for (int c = 0; c < H_ / 8; ++c) acc = dot8f(wfc_p[c * O_], hv[c], acc);
    out[(size_t)b * O_ + j] = acc;
  }
}

// ---------- tier-4: fp32, zero ws ----------
__global__ __launch_bounds__(1024) void rnn_fp32(
    const float* __restrict__ x,
    const float* __restrict__ Wih, const float* __restrict__ Whh,
    const float* __restrict__ bih, const float* __restrict__ bhh,
    const float* __restrict__ Wfc, const float* __restrict__ bfc,
    float* __restrict__ out) {
  __shared__ float hs[H_];
  __shared__ float xs[I_];
  const int b = blockIdx.x;
  const int j = threadIdx.x;
  const float bias = bih[j] + bhh[j];
  hs[j] = 0.f;
  const float4* wih_r = reinterpret_cast<const float4*>(Wih + (size_t)j * I_);
  const float4* whh_r = reinterpret_cast<const float4*>(Whh + (size_t)j * H_);
  const float4* xv = reinterpret_cast<const float4*>(xs);
  const float4* hv = reinterpret_cast<const float4*>(hs);
  const float* xrow = x + (size_t)b * T_ * I_;
  for (int t = 0; t < T_; ++t) {
    if (j < I_) xs[j] = xrow[t * I_ + j];
    __syncthreads();
    float acc = bias;
#pragma unroll 4
    for (int c = 0; c < I_ / 4; ++c) {
      float4 w = wih_r[c], v = xv[c];
      acc = fmaf(w.x, v.x, acc); acc = fmaf(w.y, v.y, acc);
      acc = fmaf(w.z, v.z, acc); acc = fmaf(w.w, v.w, acc);
    }
#pragma unroll 4
    for (int c = 0; c < H_ / 4; ++c) {
      float4 w = whh_r[c], v = hv[c];
      acc = fmaf(w.x, v.x, acc); acc = fmaf(w.y, v.y, acc);
      acc = fmaf(w.z, v.z, acc); acc = fmaf(w.w, v.w, acc);
    }
    float hn = tanhf(acc);
    __syncthreads();
    hs[j] = hn;
  }
  __syncthreads();
  if (j < O_) {
    float acc = bfc[j];
    const float4* wfc_r = reinterpret_cast<const float4*>(Wfc + (size_t)j * H_);
    for (int c = 0; c < H_ / 4; ++c) {
      float4 w = wfc_r[c], v = hv[c];
      acc = fmaf(w.x, v.x, acc); acc = fmaf(w.y, v.y, acc);
      acc = fmaf(w.z, v.z, acc); acc = fmaf(w.w, v.w, acc);
    }
    out[(size_t)b * O_ + j] = acc;
  }
}

extern "C" void kernel_launch(void* const* d_in, const int* in_sizes, int n_in,
                              void* d_out, int out_size, void* d_ws, size_t ws_size,
                              hipStream_t stream) {
  const float* x   = (const float*)d_in[0];
  const float* Wih = (const float*)d_in[1];
  const float* Whh = (const float*)d_in[2];
  const float* bih = (const float*)d_in[3];
  const float* bhh = (const float*)d_in[4];
  const float* Wfc = (const float*)d_in[5];
  const float* bfc = (const float*)d_in[6];
  float* out = (float*)d_out;

  const size_t n_whh = (size_t)H_ * H_;
  const size_t n_wih = (size_t)H_ * I_;
  const size_t n_wfc = (size_t)O_ * H_;
  const size_t n_x   = (size_t)B_ * T_ * I_;
  const size_t n_hseq = (size_t)T_ * NCLUST * MB * H_;
  const int thr = 256;

  // ---- tier 1 layout: whh | wih | wfcT | xbf | hseq  (~83 MB)
  {
    size_t off = 0;
    const size_t o_whh = off; off += n_whh;
    const size_t o_wih = off; off += n_wih;
    const size_t o_wfc = off; off += n_wfc;
    const size_t o_x   = off; off += n_x;
    const size_t o_hs  = off; off += n_hseq;
    const size_t need1 = off * sizeof(f16);

    if (ws_size >= need1) {
      f16* wsf   = (f16*)d_ws;
      f16* whh_h = wsf + o_whh;
      f16* wih_h = wsf + o_wih;
      f16* wfcT  = wsf + o_wfc;
      f16* xbf   = wsf + o_x;
      f16* hseq  = wsf + o_hs;

      const long n16 = (long)(n_hseq * sizeof(f16) / 16);
      init_hseq<<<4096, thr, 0, stream>>>((unsigned*)hseq, n16);
      cast_f16<<<(int)(n_whh / 4 / thr), thr, 0, stream>>>(Whh, whh_h, (int)(n_whh / 4));
      cast_f16<<<(int)(n_wih / 4 / thr), thr, 0, stream>>>(Wih, wih_h, (int)(n_wih / 4));
      cast_f16<<<(int)(n_x / 4 / thr), thr, 0, stream>>>(x, xbf, (int)(n_x / 4));
      convert_T8<<<(int)(n_wfc / 8 / thr), thr, 0, stream>>>(Wfc, wfcT, O_, H_);

      rnn11<<<NCLUST * WPC, thr, 0, stream>>>(whh_h, wih_h, xbf, bih, bhh, hseq);
      const f16* hlast = hseq + (size_t)(T_ - 1) * NCLUST * MB * H_;
      fc_head_flat<<<B_, O_, 0, stream>>>(hlast, wfcT, bfc, out);
      return;
    }
  }

  // ---- tier 3 (3 MB) / tier 4 (0)
  if (ws_size >= (n_wih + n_whh + n_wfc) * sizeof(f16)) {
    f16* wihT = (f16*)d_ws;
    f16* whhT = wihT + n_wih;
    f16* wfcT = whhT + n_whh;
    convert_T8<<<(int)((n_wih / 8 + thr - 1) / thr), thr, 0, stream>>>(Wih, wihT, H_, I_);
    convert_T8<<<(int)((n_whh / 8 + thr - 1) / thr), thr, 0, stream>>>(Whh, whhT, H_, H_);
    convert_T8<<<(int)((n_wfc / 8 + thr - 1) / thr), thr, 0, stream>>>(Wfc, wfcT, O_, H_);
    rnn_f16<<<B_, 1024, 0, stream>>>(x, wihT, whhT, bih, bhh, wfcT, bfc, out);
  } else {
    rnn_fp32<<<B_, 1024, 0, stream>>>(x, Wih, Whh, bih, bhh, Wfc, bfc, out);
  }
}

// Round 12
// 1145.882 us; speedup vs baseline: 1.8884x; 1.3655x over previous
//
#include <hip/hip_runtime.h>

#define B_ 64
#define T_ 512
#define I_ 256
#define H_ 1024
#define O_ 256

#define NCLUST 4
#define WPC 64        // workgroups per cluster (validated optimum: r6 vs r8/r9)
#define MB 16         // batches per cluster
#define ROWS 16       // h-rows per WG
#define NMF_H 8       // h-part MFMAs per wave (K=256)
#define NMF_X 2       // x-part MFMAs per wave (K=64)
#define KPW_H 256
#define KPW_X 64
#define SENT 0x7FFF7FFFu   // f16 NaN pair: tanh output can never equal this

typedef _Float16 f16;
typedef _Float16 f16x2 __attribute__((ext_vector_type(2)));
typedef _Float16 f16x4 __attribute__((ext_vector_type(4)));
typedef _Float16 half8 __attribute__((ext_vector_type(8)));
typedef float floatx4 __attribute__((ext_vector_type(4)));
typedef unsigned int uint4v __attribute__((ext_vector_type(4)));

// ---------- memory helpers ----------
// sc0 sc1 loads: bypass L1+L2, read at MALL (device coherence point).
__device__ __forceinline__ uint4v load_uc16(const void* p) {
  uint4v r;
  asm volatile("global_load_dwordx4 %0, %1, off sc0 sc1" : "=v"(r) : "v"(p));
  return r;
}
__device__ __forceinline__ void store_uc16(void* p, uint4v v) {
  asm volatile("global_store_dwordx4 %0, %1, off sc0 sc1" :: "v"(p), "v"(v) : "memory");
}
// ATOMIC publish (r12 key change): global_atomic_swap executes AT the MALL and
// leaves the line resident there (an atomic must own the line — it cannot
// write-through-and-invalidate like the sc1 store does, which r11's FETCH
// counter proved costs an HBM round trip per step). No return (no sc0).
__device__ __forceinline__ void publish4(void* p, unsigned v) {
  asm volatile("global_atomic_swap %0, %1, off" :: "v"(p), "v"(v) : "memory");
}
__device__ __forceinline__ unsigned pack_f16x2(float a, float b) {
  f16x2 t; t[0] = (f16)a; t[1] = (f16)b;
  return __builtin_bit_cast(unsigned, t);
}

// fast tanh: 1 - 2/(e^(2x)+1) via v_exp_f32 + v_rcp_f32 (validated r10)
__device__ __forceinline__ float fast_tanh(float x) {
#if __has_builtin(__builtin_amdgcn_exp2f) && __has_builtin(__builtin_amdgcn_rcpf)
  float e = __builtin_amdgcn_exp2f(x * 2.8853900817779268f);  // 2*log2(e)
  return 1.0f - 2.0f * __builtin_amdgcn_rcpf(e + 1.0f);
#else
  return tanhf(x);
#endif
}

#if __has_builtin(__builtin_amdgcn_fdot2)
__device__ __forceinline__ float dot2f(f16x2 a, f16x2 b, float c) {
  return __builtin_amdgcn_fdot2(a, b, c, false);
}
#else
__device__ __forceinline__ float dot2f(f16x2 a, f16x2 b, float c) {
  return fmaf((float)a[0], (float)b[0], fmaf((float)a[1], (float)b[1], c));
}
#endif

__device__ __forceinline__ float dot8f(half8 w, half8 v, float acc) {
  acc = dot2f(__builtin_shufflevector(w, w, 0, 1), __builtin_shufflevector(v, v, 0, 1), acc);
  acc = dot2f(__builtin_shufflevector(w, w, 2, 3), __builtin_shufflevector(v, v, 2, 3), acc);
  acc = dot2f(__builtin_shufflevector(w, w, 4, 5), __builtin_shufflevector(v, v, 4, 5), acc);
  acc = dot2f(__builtin_shufflevector(w, w, 6, 7), __builtin_shufflevector(v, v, 6, 7), acc);
  return acc;
}

// ---------- converters / init ----------
__global__ void cast_f16(const float* __restrict__ src, f16* __restrict__ dst, int n4) {
  int i = blockIdx.x * blockDim.x + threadIdx.x;
  if (i >= n4) return;
  float4 a = reinterpret_cast<const float4*>(src)[i];
  f16x4 v;
  v[0] = (f16)a.x; v[1] = (f16)a.y; v[2] = (f16)a.z; v[3] = (f16)a.w;
  reinterpret_cast<f16x4*>(dst)[i] = v;
}

__global__ void convert_T8(const float* __restrict__ src, f16* __restrict__ dst,
                           int R, int K) {
  int K8 = K >> 3;
  int total = R * K8;
  int idx = blockIdx.x * blockDim.x + threadIdx.x;
  if (idx >= total) return;
  int r = idx / K8;
  int k8 = idx - r * K8;
  const float4* s = reinterpret_cast<const float4*>(src + (size_t)r * K + (size_t)k8 * 8);
  float4 a = s[0], b = s[1];
  half8 v;
  v[0] = (f16)a.x; v[1] = (f16)a.y; v[2] = (f16)a.z; v[3] = (f16)a.w;
  v[4] = (f16)b.x; v[5] = (f16)b.y; v[6] = (f16)b.z; v[7] = (f16)b.w;
  reinterpret_cast<half8*>(dst)[(size_t)k8 * R + r] = v;
}

// sentinel-fill hseq via MALL bypass stores; re-run every launch (replay-safe)
__global__ void init_hseq(unsigned* __restrict__ p, long n16) {
  uint4v sv; sv[0] = SENT; sv[1] = SENT; sv[2] = SENT; sv[3] = SENT;
  long i = (long)blockIdx.x * blockDim.x + threadIdx.x;
  const long stride = (long)gridDim.x * blockDim.x;
  for (; i < n16; i += stride) store_uc16(p + 4 * i, sv);
}

// ---------- tier-1 recurrent kernel: r6 sentinel dataflow + atomic publish ----------
// grid 256 x 256 thr. Cluster c = wg&3 owns batches [c*16,+16); worker w = wg>>2
// owns h rows [w*16,+16). W_hh/W_ih slices stationary in VGPRs; h[s] in hseq[s-1]
// (unique per step, sentinel-filled). Producer: ATOMIC-SWAP h dwords (fire-and-
// forget; data IS the flag; line stays MALL-resident). Consumer: merged
// poll+load from MALL, retry until no sentinel dword.
__global__ __launch_bounds__(256) void rnn12(
    const f16* __restrict__ whh,   // [H][H] f16
    const f16* __restrict__ wih,   // [H][I] f16
    const f16* __restrict__ xbf,   // [B][T][I] f16
    const float* __restrict__ bih,
    const float* __restrict__ bhh,
    f16* __restrict__ hseq) {      // [T][NCLUST][MB][H] f16 (sentinel-filled)
  const int wg = blockIdx.x;
  const int c = wg & 3;
  const int w = wg >> 2;
  const int tid = threadIdx.x;
  const int wv = tid >> 6;
  const int lane = tid & 63;
  const int lr = lane & 15;
  const int kb = lane >> 4;
  const int n0 = w * ROWS;
  const int b0 = c * MB;

  // stationary B-fragments
  half8 bfh[NMF_H];
#pragma unroll
  for (int i = 0; i < NMF_H; ++i) {
    const int k = wv * KPW_H + i * 32 + kb * 8;
    bfh[i] = *reinterpret_cast<const half8*>(&whh[(size_t)(n0 + lr) * H_ + k]);
  }
  half8 bfx[NMF_X];
#pragma unroll
  for (int i = 0; i < NMF_X; ++i) {
    const int k = wv * KPW_X + i * 32 + kb * 8;
    bfx[i] = *reinterpret_cast<const half8*>(&wih[(size_t)(n0 + lr) * I_ + k]);
  }

  // output ownership after the K-split reduce (validated mapping)
  const int m = ((lane >> 4) << 2) | wv;
  const int nl = lane & 15;
  const float bias = bih[n0 + nl] + bhh[n0 + nl];

  const f16* xrow = xbf + (size_t)(b0 + lr) * T_ * I_ + wv * KPW_X + kb * 8;

  __shared__ floatx4 red[2][4][64];   // parity double-buffer: 1 barrier/step
  const size_t CST = (size_t)NCLUST * MB * H_;
  const size_t coff = (size_t)c * MB * H_;

  for (int s = 1; s <= T_; ++s) {
    // x loads (cached) issued first: latency hides under the poll
    const f16* xs = xrow + (size_t)(s - 1) * I_;
    half8 ax0 = *reinterpret_cast<const half8*>(xs);
    half8 ax1 = *reinterpret_cast<const half8*>(xs + 32);

    floatx4 acc0 = {0.f, 0.f, 0.f, 0.f}, acc1 = {0.f, 0.f, 0.f, 0.f};
    acc0 = __builtin_amdgcn_mfma_f32_16x16x32_f16(ax0, bfx[0], acc0, 0, 0, 0);
    acc1 = __builtin_amdgcn_mfma_f32_16x16x32_f16(ax1, bfx[1], acc1, 0, 0, 0);

    if (s > 1) {
      const f16* hr = hseq + (size_t)(s - 2) * CST + coff;  // h[s-1]
      uint4v af[NMF_H];
      int g = 0;
      for (;;) {
        // merged poll+load: fetch all 8 packets from MALL
#pragma unroll
        for (int i = 0; i < NMF_H; ++i) {
          const int k = wv * KPW_H + i * 32 + kb * 8;
          af[i] = load_uc16(&hr[(size_t)lr * H_ + k]);
        }
        asm volatile("s_waitcnt vmcnt(0)" ::: "memory");
        unsigned bad = 0u;
#pragma unroll
        for (int i = 0; i < NMF_H; ++i) {
          bad |= (unsigned)(af[i][0] == SENT);
          bad |= (unsigned)(af[i][1] == SENT);
          bad |= (unsigned)(af[i][2] == SENT);
          bad |= (unsigned)(af[i][3] == SENT);
        }
        if (__all(bad == 0u)) break;            // all dwords written -> data valid
        if (++g > (1 << 14)) break;             // fail-fast valve (no hang)
        __builtin_amdgcn_s_sleep(1);
      }
      __builtin_amdgcn_sched_barrier(0);
#pragma unroll
      for (int i = 0; i < NMF_H; ++i) {
        half8 a = __builtin_bit_cast(half8, af[i]);
        if (i & 1) acc1 = __builtin_amdgcn_mfma_f32_16x16x32_f16(a, bfh[i], acc1, 0, 0, 0);
        else       acc0 = __builtin_amdgcn_mfma_f32_16x16x32_f16(a, bfh[i], acc0, 0, 0, 0);
      }
    }

    // K-split reduce (parity-buffered: single barrier per step)
    const int pr = s & 1;
    red[pr][wv][lane] = acc0 + acc1;
    __syncthreads();

    float v = red[pr][0][lane][wv] + red[pr][1][lane][wv] +
              red[pr][2][lane][wv] + red[pr][3][lane][wv] + bias;
    float hn = fast_tanh(v);
    float po = __shfl_xor(hn, 1);
    f16* hw = hseq + (size_t)(s - 1) * CST + coff;
    if (!(lane & 1)) {
      publish4(&hw[(size_t)m * H_ + n0 + nl], pack_f16x2(hn, po));
    }
    // fire-and-forget: data IS the flag; atomic keeps the line at MALL.
  }
}

// FC head over flat h_last rows: row b at hlast + b*H_
__global__ __launch_bounds__(256) void fc_head_flat(
    const f16* __restrict__ hlast, const f16* __restrict__ wfcT,
    const float* __restrict__ bfc, float* __restrict__ out) {
  __shared__ f16 hs[H_];
  const int b = blockIdx.x;
  const int o = threadIdx.x;
  reinterpret_cast<f16x4*>(hs)[o] =
      reinterpret_cast<const f16x4*>(hlast + (size_t)b * H_)[o];
  __syncthreads();
  float acc = bfc[o];
  const half8* wp = reinterpret_cast<const half8*>(wfcT) + o;
  const half8* hv = reinterpret_cast<const half8*>(hs);
#pragma unroll 8
  for (int c8 = 0; c8 < H_ / 8; ++c8) acc = dot8f(wp[(size_t)c8 * O_], hv[c8], acc);
  out[(size_t)b * O_ + o] = acc;
}

// ---------- tier-3: round-1 weight-streaming (3 MB ws) ----------
__global__ __launch_bounds__(1024) void rnn_f16(
    const float* __restrict__ x, const f16* __restrict__ wihT,
    const f16* __restrict__ whhT, const float* __restrict__ bih,
    const float* __restrict__ bhh, const f16* __restrict__ wfcT,
    const float* __restrict__ bfc, float* __restrict__ out) {
  __shared__ f16 hs[H_];
  __shared__ f16 xs[I_];
  const int b = blockIdx.x;
  const int j = threadIdx.x;
  const float bias = bih[j] + bhh[j];
  hs[j] = (f16)0.f;
  const half8* wih_p = reinterpret_cast<const half8*>(wihT) + j;
  const half8* whh_p = reinterpret_cast<const half8*>(whhT) + j;
  const half8* xv = reinterpret_cast<const half8*>(xs);
  const half8* hv = reinterpret_cast<const half8*>(hs);
  const float* xrow = x + (size_t)b * T_ * I_;
  for (int t = 0; t < T_; ++t) {
    if (j < I_) xs[j] = (f16)xrow[t * I_ + j];
    __syncthreads();
    float acc = bias;
#pragma unroll 8
    for (int c = 0; c < I_ / 8; ++c) acc = dot8f(wih_p[c * H_], xv[c], acc);
#pragma unroll 8
    for (int c = 0; c < H_ / 8; ++c) acc = dot8f(whh_p[c * H_], hv[c], acc);
    float hn = tanhf(acc);
    __syncthreads();
    hs[j] = (f16)hn;
  }
  __syncthreads();
  if (j < O_) {
    const half8* wfc_p = reinterpret_cast<const half8*>(wfcT) + j;
    float acc = bfc[j];
#pragma unroll 8
    for (int c = 0; c < H_ / 8; ++c) acc = dot8f(wfc_p[c * O_], hv[c], acc);
    out[(size_t)b * O_ + j] = acc;
  }
}

// ---------- tier-4: fp32, zero ws ----------
__global__ __launch_bounds__(1024) void rnn_fp32(
    const float* __restrict__ x,
    const float* __restrict__ Wih, const float* __restrict__ Whh,
    const float* __restrict__ bih, const float* __restrict__ bhh,
    const float* __restrict__ Wfc, const float* __restrict__ bfc,
    float* __restrict__ out) {
  __shared__ float hs[H_];
  __shared__ float xs[I_];
  const int b = blockIdx.x;
  const int j = threadIdx.x;
  const float bias = bih[j] + bhh[j];
  hs[j] = 0.f;
  const float4* wih_r = reinterpret_cast<const float4*>(Wih + (size_t)j * I_);
  const float4* whh_r = reinterpret_cast<const float4*>(Whh + (size_t)j * H_);
  const float4* xv = reinterpret_cast<const float4*>(xs);
  const float4* hv = reinterpret_cast<const float4*>(hs);
  const float* xrow = x + (size_t)b * T_ * I_;
  for (int t = 0; t < T_; ++t) {
    if (j < I_) xs[j] = xrow[t * I_ + j];
    __syncthreads();
    float acc = bias;
#pragma unroll 4
    for (int c = 0; c < I_ / 4; ++c) {
      float4 w = wih_r[c], v = xv[c];
      acc = fmaf(w.x, v.x, acc); acc = fmaf(w.y, v.y, acc);
      acc = fmaf(w.z, v.z, acc); acc = fmaf(w.w, v.w, acc);
    }
#pragma unroll 4
    for (int c = 0; c < H_ / 4; ++c) {
      float4 w = whh_r[c], v = hv[c];
      acc = fmaf(w.x, v.x, acc); acc = fmaf(w.y, v.y, acc);
      acc = fmaf(w.z, v.z, acc); acc = fmaf(w.w, v.w, acc);
    }
    float hn = tanhf(acc);
    __syncthreads();
    hs[j] = hn;
  }
  __syncthreads();
  if (j < O_) {
    float acc = bfc[j];
    const float4* wfc_r = reinterpret_cast<const float4*>(Wfc + (size_t)j * H_);
    for (int c = 0; c < H_ / 4; ++c) {
      float4 w = wfc_r[c], v = hv[c];
      acc = fmaf(w.x, v.x, acc); acc = fmaf(w.y, v.y, acc);
      acc = fmaf(w.z, v.z, acc); acc = fmaf(w.w, v.w, acc);
    }
    out[(size_t)b * O_ + j] = acc;
  }
}

extern "C" void kernel_launch(void* const* d_in, const int* in_sizes, int n_in,
                              void* d_out, int out_size, void* d_ws, size_t ws_size,
                              hipStream_t stream) {
  const float* x   = (const float*)d_in[0];
  const float* Wih = (const float*)d_in[1];
  const float* Whh = (const float*)d_in[2];
  const float* bih = (const float*)d_in[3];
  const float* bhh = (const float*)d_in[4];
  const float* Wfc = (const float*)d_in[5];
  const float* bfc = (const float*)d_in[6];
  float* out = (float*)d_out;

  const size_t n_whh = (size_t)H_ * H_;
  const size_t n_wih = (size_t)H_ * I_;
  const size_t n_wfc = (size_t)O_ * H_;
  const size_t n_x   = (size_t)B_ * T_ * I_;
  const size_t n_hseq = (size_t)T_ * NCLUST * MB * H_;
  const int thr = 256;

  // ---- tier 1 layout: whh | wih | wfcT | xbf | hseq  (~83 MB)
  {
    size_t off = 0;
    const size_t o_whh = off; off += n_whh;
    const size_t o_wih = off; off += n_wih;
    const size_t o_wfc = off; off += n_wfc;
    const size_t o_x   = off; off += n_x;
    const size_t o_hs  = off; off += n_hseq;
    const size_t need1 = off * sizeof(f16);

    if (ws_size >= need1) {
      f16* wsf   = (f16*)d_ws;
      f16* whh_h = wsf + o_whh;
      f16* wih_h = wsf + o_wih;
      f16* wfcT  = wsf + o_wfc;
      f16* xbf   = wsf + o_x;
      f16* hseq  = wsf + o_hs;

      const long n16 = (long)(n_hseq * sizeof(f16) / 16);
      init_hseq<<<4096, thr, 0, stream>>>((unsigned*)hseq, n16);
      cast_f16<<<(int)(n_whh / 4 / thr), thr, 0, stream>>>(Whh, whh_h, (int)(n_whh / 4));
      cast_f16<<<(int)(n_wih / 4 / thr), thr, 0, stream>>>(Wih, wih_h, (int)(n_wih / 4));
      cast_f16<<<(int)(n_x / 4 / thr), thr, 0, stream>>>(x, xbf, (int)(n_x / 4));
      convert_T8<<<(int)(n_wfc / 8 / thr), thr, 0, stream>>>(Wfc, wfcT, O_, H_);

      rnn12<<<NCLUST * WPC, thr, 0, stream>>>(whh_h, wih_h, xbf, bih, bhh, hseq);
      const f16* hlast = hseq + (size_t)(T_ - 1) * NCLUST * MB * H_;
      fc_head_flat<<<B_, O_, 0, stream>>>(hlast, wfcT, bfc, out);
      return;
    }
  }

  // ---- tier 3 (3 MB) / tier 4 (0)
  if (ws_size >= (n_wih + n_whh + n_wfc) * sizeof(f16)) {
    f16* wihT = (f16*)d_ws;
    f16* whhT = wihT + n_wih;
    f16* wfcT = whhT + n_whh;
    convert_T8<<<(int)((n_wih / 8 + thr - 1) / thr), thr, 0, stream>>>(Wih, wihT, H_, I_);
    convert_T8<<<(int)((n_whh / 8 + thr - 1) / thr), thr, 0, stream>>>(Whh, whhT, H_, H_);
    convert_T8<<<(int)((n_wfc / 8 + thr - 1) / thr), thr, 0, stream>>>(Wfc, wfcT, O_, H_);
    rnn_f16<<<B_, 1024, 0, stream>>>(x, wihT, whhT, bih, bhh, wfcT, bfc, out);
  } else {
    rnn_fp32<<<B_, 1024, 0, stream>>>(x, Wih, Whh, bih, bhh, Wfc, bfc, out);
  }
}